// Round 1
// baseline (1649.065 us; speedup 1.0000x reference)
//
#include <hip/hip_runtime.h>

// AliasFreeSampling: separable 65-tap filter (reflect pad 32) + 2x2 avg pool.
// Folded pooling: c[s] = 0.5*(k[s]+k[s-1]), s in [0,66), k[-1]=k[65]=0.
//   g[h, ow]  = sum_t c[t] * x[h, refl(2*ow + t - 32)]        (stride-2 in w)
//   out[oh,ow]= sum_s c[s] * g[refl_row(2*oh + s - 32), ow]   (stride-2 in h)

#define W_IN 512
#define H_IN 512
#define W_OUT 256
#define H_OUT 256
#define OH_T 64
#define OW_T 64
#define GROWS (2 * OH_T + 64)   // 192 g-rows per tile (incl. 64-row halo)
#define GCOLS OW_T              // 64 g-cols per tile

__global__ void afs_init_c(const float* __restrict__ k, float* __restrict__ c) {
    int i = threadIdx.x;
    if (i < 66) {
        float a = (i < 65) ? k[i] : 0.0f;
        float b = (i > 0) ? k[i - 1] : 0.0f;
        c[i] = 0.5f * (a + b);
    }
}

__device__ __forceinline__ int refl(int i, int n) {
    if (i < 0) i = -i;
    if (i >= n) i = 2 * n - 2 - i;
    return i;
}

__global__ __launch_bounds__(256) void afs_fused(
    const float* __restrict__ x, const float* __restrict__ cker,
    float* __restrict__ out) {
    __shared__ float g[GROWS][GCOLS];

    // Coefficients: uniform pointer + constant offsets -> scalar loads.
    float c[66];
#pragma unroll
    for (int i = 0; i < 66; ++i) c[i] = cker[i];

    const int plane = blockIdx.z;                    // b*32 + ch, 256 planes
    const int OH0 = blockIdx.y * OH_T;
    const int OW0 = blockIdx.x * OW_T;
    const float* xp = x + (size_t)plane * (W_IN * H_IN);
    float* op = out + (size_t)plane * (W_OUT * H_OUT);

    const int tid = threadIdx.x;

    // ---------------- Phase A: horizontal filter + w-pool -> LDS ----------
    // 192 rows * 16 col-quads = 3072 tasks; 12 per thread.
    for (int it = 0; it < (GROWS * (GCOLS / 4)) / 256; ++it) {
        int task = it * 256 + tid;
        int gr = task >> 4;        // g-row [0,192)
        int c4 = task & 15;        // col-quad [0,16)
        int h = refl(2 * OH0 - 32 + gr, H_IN);
        const float* xrow = xp + (size_t)h * W_IN;
        int W0 = 2 * OW0 + 8 * c4 - 32;  // window start (multiple of 8)

        float xw[72];
        if (W0 >= 0 && W0 + 71 < W_IN) {
            const float4* p = (const float4*)(xrow + W0);
#pragma unroll
            for (int q = 0; q < 18; ++q) {
                float4 v = p[q];
                xw[4 * q + 0] = v.x;
                xw[4 * q + 1] = v.y;
                xw[4 * q + 2] = v.z;
                xw[4 * q + 3] = v.w;
            }
        } else {
#pragma unroll
            for (int i = 0; i < 72; ++i) xw[i] = xrow[refl(W0 + i, W_IN)];
        }

        float4 acc = {0.0f, 0.0f, 0.0f, 0.0f};
#pragma unroll
        for (int t = 0; t < 66; ++t) {
            float cv = c[t];
            acc.x += cv * xw[t + 0];
            acc.y += cv * xw[t + 2];
            acc.z += cv * xw[t + 4];
            acc.w += cv * xw[t + 6];
        }
        *(float4*)&g[gr][4 * c4] = acc;
    }
    __syncthreads();

    // ---------------- Phase B: vertical filter + h-pool -> global ---------
    // Thread: 4 rows x 4 cols. 16 col-groups x 16 row-groups = 256 tasks.
    {
        const int cg = tid & 15;   // col quad [0,16)
        const int rg = tid >> 4;   // row quad [0,16)
        float4 a[4];
#pragma unroll
        for (int m = 0; m < 4; ++m) a[m] = make_float4(0.f, 0.f, 0.f, 0.f);

#pragma unroll
        for (int r = 0; r < 72; ++r) {
            float4 gv = *(const float4*)&g[8 * rg + r][4 * cg];
#pragma unroll
            for (int m = 0; m < 4; ++m) {
                const int t = r - 2 * m;   // tap index, compile-time
                if (t >= 0 && t <= 65) {
                    float cv = c[t];
                    a[m].x += cv * gv.x;
                    a[m].y += cv * gv.y;
                    a[m].z += cv * gv.z;
                    a[m].w += cv * gv.w;
                }
            }
        }

#pragma unroll
        for (int m = 0; m < 4; ++m) {
            int oh = OH0 + 4 * rg + m;
            *(float4*)(op + (size_t)oh * W_OUT + OW0 + 4 * cg) = a[m];
        }
    }
}

extern "C" void kernel_launch(void* const* d_in, const int* in_sizes, int n_in,
                              void* d_out, int out_size, void* d_ws, size_t ws_size,
                              hipStream_t stream) {
    const float* x = (const float*)d_in[0];     // (8,32,512,512) fp32
    const float* k = (const float*)d_in[1];     // (65,) fp32
    float* out = (float*)d_out;                 // (8,32,256,256) fp32
    float* c = (float*)d_ws;                    // 66 floats scratch

    afs_init_c<<<1, 128, 0, stream>>>(k, c);

    dim3 grid(W_OUT / OW_T, H_OUT / OH_T, 256); // 4 x 4 x 256
    afs_fused<<<grid, 256, 0, stream>>>(x, c, out);
}